// Round 1
// baseline (612.218 us; speedup 1.0000x reference)
//
#include <hip/hip_runtime.h>
#include <hip/hip_bf16.h>
#include <stdint.h>

typedef unsigned short ushortT;

#define MM 1024
#define NN 4096
#define DD 128
#define EPSX 0.05f
#define STRENGTH 0.5f
#define TINYX 1e-12f
#define NITER 50

// ws float-index layout
#define WS_MAXCOST 0      // float bits, via atomicMax on uint
#define WS_MAXCAP  1
#define WS_KSUM_SLOTS 16  // 64 slots
#define WS_SCORE_SLOTS 80 // 64 slots
#define WS_T_SLOTS 144    // 2 parities x 64 slots (144..271)
#define WS_U 512          // 1024 floats (u2 then u)
#define WS_V 1536         // 4096 floats (v2 then v)
#define K_BYTE_OFF 32768
#define FAST_NEED (32768ull + 2ull * 8388608ull)

__device__ inline float bf2f(ushortT u) { return __uint_as_float(((unsigned)u) << 16); }
__device__ inline ushortT f2bf(float f) {
    unsigned b = __float_as_uint(f);
    b += 0x7fffu + ((b >> 16) & 1u);
    return (ushortT)(b >> 16);
}
__device__ inline float wave_sum(float v) {
    for (int o = 32; o; o >>= 1) v += __shfl_down(v, o);
    return v;
}
__device__ inline float wave_max(float v) {
    for (int o = 32; o; o >>= 1) v = fmaxf(v, __shfl_down(v, o));
    return v;
}

// ---------------- init: zero scalars/slots, compute maxcap ----------------
__global__ void k_init(float* ws, const float* cap) {
    int t = threadIdx.x;
    for (int i = t; i < 512; i += 256) ws[i] = 0.f;
    float m = 0.f;
    for (int j = t; j < NN; j += 256) m = fmaxf(m, cap[j]);
    __shared__ float red[4];
    m = wave_max(m);
    if ((t & 63) == 0) red[t >> 6] = m;
    __syncthreads();
    if (t == 0) ws[WS_MAXCAP] = fmaxf(fmaxf(red[0], red[1]), fmaxf(red[2], red[3]));
}

// ---------------- row norms u2 / v2 (one wave per row) ----------------
__global__ void k_norms(const float* U, const float* V, float* ws) {
    int wid = threadIdx.x >> 6, lane = threadIdx.x & 63;
    int row = blockIdx.x * 4 + wid;  // 0..5119
    const float* src = (row < MM) ? (U + (size_t)row * DD) : (V + (size_t)(row - MM) * DD);
    float2 a = *(const float2*)(src + lane * 2);
    float s = a.x * a.x + a.y * a.y;
    s = wave_sum(s);
    if (lane == 0) {
        if (row < MM) ws[WS_U + row] = s;
        else          ws[WS_V + row - MM] = s;
    }
}

// ---------------- cost GEMM: 64x64 tiles, raw clamped cost -> plan region, global max ----------------
__global__ __launch_bounds__(256) void k_cost(const float* U, const float* V, float* cost, float* ws) {
    __shared__ float As[64][65];
    __shared__ float Bs[64][65];
    __shared__ float red[4];
    int t = threadIdx.x;
    int tr0 = (blockIdx.x >> 6) << 6;  // 16 row tiles
    int tc0 = (blockIdx.x & 63) << 6;  // 64 col tiles
    int tx = t & 15, ty = t >> 4;
    float acc[4][4] = {};
    for (int kk = 0; kk < DD; kk += 64) {
        for (int p = 0; p < 4; p++) {
            int f = t * 4 + p * 1024;  // 0..4095
            int r = f >> 6, k = f & 63;
            float4 av = *(const float4*)(U + (size_t)(tr0 + r) * DD + kk + k);
            As[r][k] = av.x; As[r][k + 1] = av.y; As[r][k + 2] = av.z; As[r][k + 3] = av.w;
            float4 bv = *(const float4*)(V + (size_t)(tc0 + r) * DD + kk + k);
            Bs[r][k] = bv.x; Bs[r][k + 1] = bv.y; Bs[r][k + 2] = bv.z; Bs[r][k + 3] = bv.w;
        }
        __syncthreads();
        for (int k = 0; k < 64; k++) {
            float av[4], bv[4];
#pragma unroll
            for (int i = 0; i < 4; i++) av[i] = As[ty * 4 + i][k];
#pragma unroll
            for (int j = 0; j < 4; j++) bv[j] = Bs[tx * 4 + j][k];
#pragma unroll
            for (int i = 0; i < 4; i++)
#pragma unroll
                for (int j = 0; j < 4; j++) acc[i][j] += av[i] * bv[j];
        }
        __syncthreads();
    }
    float u2[4], v2[4];
#pragma unroll
    for (int i = 0; i < 4; i++) u2[i] = ws[WS_U + tr0 + ty * 4 + i];
#pragma unroll
    for (int j = 0; j < 4; j++) v2[j] = ws[WS_V + tc0 + tx * 4 + j];
    float lmax = 0.f;
#pragma unroll
    for (int i = 0; i < 4; i++) {
        int gr = tr0 + ty * 4 + i;
#pragma unroll
        for (int j = 0; j < 4; j++) {
            float c = fmaxf(u2[i] + v2[j] - 2.f * acc[i][j], 0.f);
            lmax = fmaxf(lmax, c);
            cost[(size_t)gr * NN + tc0 + tx * 4 + j] = c;
        }
    }
    lmax = wave_max(lmax);
    if ((t & 63) == 0) red[t >> 6] = lmax;
    __syncthreads();
    if (t == 0) {
        lmax = fmaxf(fmaxf(red[0], red[1]), fmaxf(red[2], red[3]));
        atomicMax((unsigned*)&ws[WS_MAXCOST], __float_as_uint(lmax));
    }
}

// ---------------- make K (bf16) + K^T + Ksum ----------------
__global__ __launch_bounds__(256) void k_makeK(const float* cost, const float* cap, float* ws,
                                               ushortT* K, ushortT* KT) {
    __shared__ ushortT tile[64][65];
    __shared__ float red[4];
    int t = threadIdx.x;
    int tr0 = (blockIdx.x >> 6) << 6, tc0 = (blockIdx.x & 63) << 6;
    float inv_mc = 1.f / (__uint_as_float(*(const unsigned*)&ws[WS_MAXCOST]) + TINYX);
    float inv_cap = 1.f / (ws[WS_MAXCAP] + TINYX);
    float lsum = 0.f;
    for (int s = 0; s < 16; s++) {
        int lr = s * 4 + (t >> 6), lc = t & 63;
        int gr = tr0 + lr, gc = tc0 + lc;
        float c = cost[(size_t)gr * NN + gc] * inv_mc + STRENGTH * (1.f - cap[gc] * inv_cap);
        float kf = expf(-c * (1.f / EPSX));
        lsum += kf;
        ushortT kb = f2bf(kf);
        K[(size_t)gr * NN + gc] = kb;
        tile[lr][lc] = kb;
    }
    __syncthreads();
    for (int s = 0; s < 16; s++) {
        int lr = s * 4 + (t >> 6), lc = t & 63;  // lr = KT row (orig col), lc = orig row
        KT[(size_t)(tc0 + lr) * MM + tr0 + lc] = tile[lc][lr];
    }
    lsum = wave_sum(lsum);
    if ((t & 63) == 0) red[t >> 6] = lsum;
    __syncthreads();
    if (t == 0)
        atomicAdd(&ws[WS_KSUM_SLOTS + (blockIdx.x & 63)], red[0] + red[1] + red[2] + red[3]);
}

// fallback: K as f32 in-place over cost (plan region)
__global__ void k_makeK_f32(float* costK, const float* cap, float* ws) {
    __shared__ float red[4];
    int t = threadIdx.x;
    float inv_mc = 1.f / (__uint_as_float(*(const unsigned*)&ws[WS_MAXCOST]) + TINYX);
    float inv_cap = 1.f / (ws[WS_MAXCAP] + TINYX);
    float lsum = 0.f;
    for (int s = 0; s < 4; s++) {
        size_t idx = (size_t)blockIdx.x * 1024 + s * 256 + t;
        int gc = (int)(idx & (NN - 1));
        float c = costK[idx] * inv_mc + STRENGTH * (1.f - cap[gc] * inv_cap);
        float kf = expf(-c * (1.f / EPSX));
        costK[idx] = kf;
        lsum += kf;
    }
    lsum = wave_sum(lsum);
    if ((t & 63) == 0) red[t >> 6] = lsum;
    __syncthreads();
    if (t == 0)
        atomicAdd(&ws[WS_KSUM_SLOTS + (blockIdx.x & 63)], red[0] + red[1] + red[2] + red[3]);
}

// ---------------- u,v init: u=s0, v=1 ----------------
__global__ void k_init_uv(float* ws, const float* mbp) {
    __shared__ float s0s;
    int t = threadIdx.x;
    if (t < 64) {
        float s = ws[WS_KSUM_SLOTS + t];
        s = wave_sum(s);
        if (t == 0) s0s = mbp[0] / (s + TINYX);
    }
    __syncthreads();
    float s0 = s0s;
    for (int i = t; i < MM; i += 256) ws[WS_U + i] = s0;
    for (int j = t; j < NN; j += 256) ws[WS_V + j] = 1.f;
}

// ---------------- row pass: y = K v, fold g, row clip ----------------
__global__ __launch_bounds__(256) void k_row(const ushortT* K, const float* a, const float* mbp,
                                             float* ws, int iter) {
    __shared__ float red[4];
    int t = threadIdx.x, i = blockIdx.x;
    const uint4* Krow = (const uint4*)(K + (size_t)i * NN);
    const float* v = ws + WS_V;
    float s = 0.f;
#pragma unroll
    for (int p = 0; p < 2; p++) {
        int slot = t + p * 256;
        uint4 kk = Krow[slot];
        int j = slot * 8;
        float4 v0 = *(const float4*)(v + j);
        float4 v1 = *(const float4*)(v + j + 4);
        s += __uint_as_float(kk.x << 16) * v0.x + __uint_as_float(kk.x & 0xffff0000u) * v0.y;
        s += __uint_as_float(kk.y << 16) * v0.z + __uint_as_float(kk.y & 0xffff0000u) * v0.w;
        s += __uint_as_float(kk.z << 16) * v1.x + __uint_as_float(kk.z & 0xffff0000u) * v1.y;
        s += __uint_as_float(kk.w << 16) * v1.z + __uint_as_float(kk.w & 0xffff0000u) * v1.w;
    }
    s = wave_sum(s);
    if ((t & 63) == 0) red[t >> 6] = s;
    __syncthreads();
    if (blockIdx.x == 0 && t >= 64 && t < 128) ws[WS_T_SLOTS + (iter & 1) * 64 + t - 64] = 0.f;
    if (t < 64) {
        float y = red[0] + red[1] + red[2] + red[3];
        float g = 1.f;
        if (iter > 0) {
            float tp = ws[WS_T_SLOTS + ((iter - 1) & 1) * 64 + t];
            tp = wave_sum(tp);
            g = mbp[0] / (tp + TINYX);
        }
        if (t == 0) {
            float ue = ws[WS_U + i] * g;
            float r = ue * y;
            ws[WS_U + i] = ue * fminf(a[i] / (r + TINYX), 1.f);
        }
    }
}

__global__ __launch_bounds__(256) void k_row_f32(const float* K, const float* a, const float* mbp,
                                                 float* ws, int iter) {
    __shared__ float red[4];
    int t = threadIdx.x, i = blockIdx.x;
    const float* Krow = K + (size_t)i * NN;
    const float* v = ws + WS_V;
    float s = 0.f;
    for (int p = 0; p < 16; p++) {
        int j = t + p * 256;
        s += Krow[j] * v[j];
    }
    s = wave_sum(s);
    if ((t & 63) == 0) red[t >> 6] = s;
    __syncthreads();
    if (blockIdx.x == 0 && t >= 64 && t < 128) ws[WS_T_SLOTS + (iter & 1) * 64 + t - 64] = 0.f;
    if (t < 64) {
        float y = red[0] + red[1] + red[2] + red[3];
        float g = 1.f;
        if (iter > 0) {
            float tp = ws[WS_T_SLOTS + ((iter - 1) & 1) * 64 + t];
            tp = wave_sum(tp);
            g = mbp[0] / (tp + TINYX);
        }
        if (t == 0) {
            float ue = ws[WS_U + i] * g;
            float r = ue * y;
            ws[WS_U + i] = ue * fminf(a[i] / (r + TINYX), 1.f);
        }
    }
}

// ---------------- col pass: z = K^T u, col clip, accumulate t ----------------
__global__ __launch_bounds__(256) void k_col(const ushortT* KT, const float* b, float* ws,
                                             int iter, float* usage_out) {
    __shared__ float cws[4];
    int t = threadIdx.x, lane = t & 63, wid = t >> 6;
    int j = blockIdx.x * 4 + wid;
    const uint4* Kc = (const uint4*)(KT + (size_t)j * MM);
    const float* u = ws + WS_U;
    float s = 0.f;
#pragma unroll
    for (int p = 0; p < 2; p++) {
        int slot = lane + p * 64;
        uint4 kk = Kc[slot];
        int i = slot * 8;
        float4 u0 = *(const float4*)(u + i);
        float4 u1 = *(const float4*)(u + i + 4);
        s += __uint_as_float(kk.x << 16) * u0.x + __uint_as_float(kk.x & 0xffff0000u) * u0.y;
        s += __uint_as_float(kk.y << 16) * u0.z + __uint_as_float(kk.y & 0xffff0000u) * u0.w;
        s += __uint_as_float(kk.z << 16) * u1.x + __uint_as_float(kk.z & 0xffff0000u) * u1.y;
        s += __uint_as_float(kk.w << 16) * u1.z + __uint_as_float(kk.w & 0xffff0000u) * u1.w;
    }
    s = wave_sum(s);
    if (lane == 0) {
        float vj = ws[WS_V + j];
        float c = vj * s;
        float sc = fminf(b[j] / (c + TINYX), 1.f);
        ws[WS_V + j] = vj * sc;
        float cw = c * sc;
        cws[wid] = cw;
        if (usage_out) usage_out[j] = cw;
    }
    __syncthreads();
    if (t == 0)
        atomicAdd(&ws[WS_T_SLOTS + (iter & 1) * 64 + (blockIdx.x & 63)],
                  cws[0] + cws[1] + cws[2] + cws[3]);
}

__global__ __launch_bounds__(256) void k_col_f32(const float* K, const float* b, float* ws,
                                                 int iter, float* usage_out) {
    __shared__ float red[4];
    int t = threadIdx.x;
    int j = blockIdx.x * 256 + t;  // 16 blocks
    const float* u = ws + WS_U;
    float s = 0.f;
    for (int i = 0; i < MM; i++) s += K[(size_t)i * NN + j] * u[i];
    float vj = ws[WS_V + j];
    float c = vj * s;
    float sc = fminf(b[j] / (c + TINYX), 1.f);
    ws[WS_V + j] = vj * sc;
    float cw = c * sc;
    if (usage_out) usage_out[j] = cw;
    float bs = wave_sum(cw);
    if ((t & 63) == 0) red[t >> 6] = bs;
    __syncthreads();
    if (t == 0)
        atomicAdd(&ws[WS_T_SLOTS + (iter & 1) * 64 + (blockIdx.x & 63)],
                  red[0] + red[1] + red[2] + red[3]);
}

// ---------------- writeback: plan = K*u*v, score = EPS * sum(p * ln K) ----------------
__global__ __launch_bounds__(256) void k_write(const ushortT* K, float* ws, float* outp) {
    __shared__ float red[4];
    int t = threadIdx.x;
    int i = blockIdx.x >> 2, q = (blockIdx.x & 3) * 1024;
    float ui = ws[WS_U + i];
    const ushortT* Kr = K + (size_t)i * NN + q;
    float* Pr = outp + 1 + (size_t)i * NN + q;
    const float* v = ws + WS_V + q;
    float sc = 0.f;
#pragma unroll
    for (int s = 0; s < 4; s++) {
        int j = t + s * 256;
        float kf = bf2f(Kr[j]);
        float p = kf * ui * v[j];
        Pr[j] = p;
        sc += p * __logf(kf);
    }
    sc = wave_sum(sc);
    if ((t & 63) == 0) red[t >> 6] = sc;
    __syncthreads();
    if (t == 0)
        atomicAdd(&ws[WS_SCORE_SLOTS + (blockIdx.x & 63)], red[0] + red[1] + red[2] + red[3]);
}

__global__ __launch_bounds__(256) void k_write_f32(float* K /* = plan region */, float* ws) {
    __shared__ float red[4];
    int t = threadIdx.x;
    float sc = 0.f;
    for (int s = 0; s < 4; s++) {
        size_t idx = (size_t)blockIdx.x * 256 + (size_t)s * 1048576 + t;
        int i = (int)(idx >> 12), j = (int)(idx & (NN - 1));
        float kf = K[idx];
        float p = kf * ws[WS_U + i] * ws[WS_V + j];
        K[idx] = p;
        sc += p * __logf(kf);
    }
    sc = wave_sum(sc);
    if ((t & 63) == 0) red[t >> 6] = sc;
    __syncthreads();
    if (t == 0)
        atomicAdd(&ws[WS_SCORE_SLOTS + (blockIdx.x & 63)], red[0] + red[1] + red[2] + red[3]);
}

// ---------------- epilogue: score & transported mass ----------------
__global__ void k_epi(const float* ws, float* out) {
    int t = threadIdx.x;  // 64
    float s = ws[WS_SCORE_SLOTS + t];
    s = wave_sum(s);
    float tt = ws[WS_T_SLOTS + (NITER & 1) * 64 + t];
    tt = wave_sum(tt);
    if (t == 0) {
        out[0] = EPSX * s;
        out[1 + (size_t)MM * NN] = tt;
    }
}

extern "C" void kernel_launch(void* const* d_in, const int* in_sizes, int n_in,
                              void* d_out, int out_size, void* d_ws, size_t ws_size,
                              hipStream_t stream) {
    const float* U = (const float*)d_in[0];
    const float* V = (const float*)d_in[1];
    const float* a = (const float*)d_in[2];
    const float* b = (const float*)d_in[3];
    const float* mb = (const float*)d_in[4];
    float* out = (float*)d_out;
    float* ws = (float*)d_ws;
    float* plan = out + 1;
    float* usage = out + 2 + (size_t)MM * NN;

    bool fast = (ws_size >= FAST_NEED);
    ushortT* K = (ushortT*)((char*)d_ws + K_BYTE_OFF);
    ushortT* KT = K + (size_t)MM * NN;

    k_init<<<1, 256, 0, stream>>>(ws, b);
    k_norms<<<1280, 256, 0, stream>>>(U, V, ws);
    k_cost<<<1024, 256, 0, stream>>>(U, V, plan, ws);

    if (fast) {
        k_makeK<<<1024, 256, 0, stream>>>(plan, b, ws, K, KT);
        k_init_uv<<<1, 256, 0, stream>>>(ws, mb);
        for (int it = 0; it <= NITER; it++) {
            k_row<<<MM, 256, 0, stream>>>(K, a, mb, ws, it);
            k_col<<<NN / 4, 256, 0, stream>>>(KT, b, ws, it, (it == NITER) ? usage : nullptr);
        }
        k_write<<<MM * 4, 256, 0, stream>>>(K, ws, out);
    } else {
        k_makeK_f32<<<4096, 256, 0, stream>>>(plan, b, ws);
        k_init_uv<<<1, 256, 0, stream>>>(ws, mb);
        for (int it = 0; it <= NITER; it++) {
            k_row_f32<<<MM, 256, 0, stream>>>(plan, a, mb, ws, it);
            k_col_f32<<<NN / 256, 256, 0, stream>>>(plan, b, ws, it, (it == NITER) ? usage : nullptr);
        }
        k_write_f32<<<4096, 256, 0, stream>>>(plan, ws);
    }
    k_epi<<<1, 64, 0, stream>>>(ws, out);
}